// Round 5
// baseline (1741.147 us; speedup 1.0000x reference)
//
#include <hip/hip_runtime.h>
#include <stdint.h>

// ---------------- problem constants ----------------
#define NFRAMES 2
#define NPROP   16384
#define NROWS   (NFRAMES * NPROP)        // 32768
#define DIN_    1024
#define HDIM    512
#define NCLS    11
#define LRLD    128                      // padded cols of [logits(11) | reg(99) | pad]
#define NBINS   8192
#define CAP     4096                     // gathered candidate capacity per frame
#define TGT     1024                     // target top-N for NMS scan
#define KKEEP   100
#define SCORE_T 0.05f
#define NMS_T   0.5f
#define CLIPV   4.135166556742356f       // log(1000/16)
#define BK      16

// ---------------- workspace layout (bytes) ----------------
#define OFF_H1      0ULL                           // 32768*512 f32
#define OFF_H2      67108864ULL                    // 32768*512 f32
#define OFF_LR      134217728ULL                   // 32768*128 f32
#define OFF_WCAT    150994944ULL                   // 512*128 f32
#define OFF_BCAT    151257088ULL                   // 128 f32 (padded)
#define OFF_SCORES  151258112ULL                   // 32768*10 f32
#define OFF_HIST    152568832ULL                   // 2*8192 i32
#define OFF_GCNT    152634368ULL                   // 2 i32
#define OFF_TAU     152634376ULL                   // 2 i32
#define OFF_GKEYS   152634624ULL                   // 2*4096 u64
#define WS_NEEDED   152700160ULL

// async global->LDS DMA, 16B per lane (dest = wave-uniform base + lane*16)
#define GLD16(gp, lp)                                                         \
    __builtin_amdgcn_global_load_lds(                                         \
        (const __attribute__((address_space(1))) void*)(gp),                  \
        (__attribute__((address_space(3))) void*)(lp), 16, 0, 0)

// compile-time float4 component select (folds under full unroll)
__device__ __forceinline__ float f4c(const float4& v, int i) {
    return i == 0 ? v.x : (i == 1 ? v.y : (i == 2 ? v.z : v.w));
}

// ---------------- box decode (must match reference float ops) ----------------
__device__ __forceinline__ void decode4(const float* __restrict__ prop,
                                        const float* __restrict__ rg,
                                        float& x1, float& y1, float& x2, float& y2) {
    float w  = prop[2] - prop[0];
    float h  = prop[3] - prop[1];
    float cx = prop[0] + 0.5f * w;
    float cy = prop[1] + 0.5f * h;
    float dx = rg[0] / 10.0f;
    float dy = rg[1] / 10.0f;
    float dw = fminf(rg[2] / 5.0f, CLIPV);
    float dh = fminf(rg[3] / 5.0f, CLIPV);
    float pcx = dx * w + cx;
    float pcy = dy * h + cy;
    float pw  = expf(dw) * w;
    float ph  = expf(dh) * h;
    x1 = pcx - 0.5f * pw;
    y1 = pcy - 0.5f * ph;
    x2 = pcx + 0.5f * pw;
    y2 = pcy + 0.5f * ph;
}

// ---------------- fp32 GEMM (wide): C[M,N] = act(A[M,K]@B[K,N] + bias) ----------------
// R7: 256x256 block tile, 16x16 register tile, global_load_lds staging.
// R4-R6 post-mortem: 8x16 (ceiling 89%) lost to 8x8 (ceiling 67%) because the HIP
// compiler won't spend registers on pipelining (allocated 148-168 of a 512 cap ->
// serial {reads -> lgkmcnt -> FMA} per kq, latency exposed at 1-2 waves/SIMD).
// 16x16 makes scheduling quality irrelevant: per kk, LDS = 8 reads * 12cyc = 96cyc/CU
// < VALU 512cyc/SIMD (ceiling 100%), and per kq a worst-case serialized read batch
// (20 reads, ~300cyc) amortizes over 2048 FMA cyc (~13% max loss).
// acc 256 + av 64 + B 16 + addr ~= 380 VGPR -> 1 wave/SIMD (insensitive: compute per
// batch is huge; DMA prefetch spans 8192 cyc of compute). Grid = 256 blocks = 1/CU.
// A layout: As[m][kc] row-major, XOR chunk swizzle phys = logical ^ ((m>>2)&3) on
// both global source and read (R6-verified: SQ_LDS_BANK_CONFLICT = 0).
// Per-output k-order unchanged (ascending fp32 fmac) => bitwise-identical output.
template<int K, int N, int DO_RELU>
__global__ __launch_bounds__(256, 1) void gemm512g(const float* __restrict__ A,
                                                   const float* __restrict__ B,
                                                   const float* __restrict__ bias,
                                                   float* __restrict__ C) {
    __shared__ float As[2][256][BK];   // 32 KB, row-major, k-chunk swizzled
    __shared__ float Bs[2][BK][256];   // 32 KB
    const int tid  = threadIdx.x;
    const int w    = tid >> 6;          // wave 0..3
    const int lane = tid & 63;
    const int row0 = blockIdx.x * 256;
    const int col0 = blockIdx.y * 256;
    const int tx = tid & 15, ty = tid >> 4;

    // A staging: wave w, inst j in {0..3} covers rows w*64+j*16 .. +15.
    // lane -> row +(lane>>2), phys chunk lane&3; source logical chunk XOR-swizzled
    // so the LDS dest stays lane-linear (16B per lane).
    const int a_row = w * 64 + (lane >> 2);
    const int a_kc  = ((lane & 3) ^ ((lane >> 4) & 3)) * 4;
    // B staging: inst j covers k-row w*4+j, lane -> 4 floats at lane*4.
    const int b_k   = w * 4;

    const float* Asrc = A + (size_t)(row0 + a_row) * K + a_kc;
    const float* Bsrc = B + col0 + (lane << 2);

#define STAGE(buf, kb)                                                        \
    do {                                                                      \
        GLD16(Asrc + (kb) + (size_t)(0 * 16) * K, &As[buf][w * 64 +  0][0]);  \
        GLD16(Asrc + (kb) + (size_t)(1 * 16) * K, &As[buf][w * 64 + 16][0]);  \
        GLD16(Asrc + (kb) + (size_t)(2 * 16) * K, &As[buf][w * 64 + 32][0]);  \
        GLD16(Asrc + (kb) + (size_t)(3 * 16) * K, &As[buf][w * 64 + 48][0]);  \
        GLD16(Bsrc + (size_t)((kb) + b_k + 0) * N, &Bs[buf][b_k + 0][0]);     \
        GLD16(Bsrc + (size_t)((kb) + b_k + 1) * N, &Bs[buf][b_k + 1][0]);     \
        GLD16(Bsrc + (size_t)((kb) + b_k + 2) * N, &Bs[buf][b_k + 2][0]);     \
        GLD16(Bsrc + (size_t)((kb) + b_k + 3) * N, &Bs[buf][b_k + 3][0]);     \
    } while (0)

    float acc[16][16];
#pragma unroll
    for (int i = 0; i < 16; ++i)
#pragma unroll
        for (int j = 0; j < 16; ++j) acc[i][j] = 0.f;

    STAGE(0, 0);
    __syncthreads();

    const int cswz = ty & 3;            // A-read chunk XOR for this thread's rows
    int p = 0;
    for (int k0 = 0; k0 < K; k0 += BK) {
        const bool has_next = (k0 + BK) < K;
        if (has_next) STAGE(p ^ 1, k0 + BK);   // DMA next tile; lands before next barrier
#pragma unroll
        for (int kq = 0; kq < 4; ++kq) {
            float4 av[16];                      // A[m][kq*4..+3] for this thread's 16 rows
            const int pc = (kq ^ cswz) * 4;     // physical chunk (float offset)
#pragma unroll
            for (int qi = 0; qi < 4; ++qi)
#pragma unroll
                for (int i = 0; i < 4; ++i)
                    av[qi * 4 + i] = *(const float4*)&As[p][qi * 64 + ty * 4 + i][pc];
#pragma unroll
            for (int t = 0; t < 4; ++t) {
                const int kk = kq * 4 + t;
                float4 y0 = *(const float4*)&Bs[p][kk][tx * 4];
                float4 y1 = *(const float4*)&Bs[p][kk][64 + tx * 4];
                float4 y2 = *(const float4*)&Bs[p][kk][128 + tx * 4];
                float4 y3 = *(const float4*)&Bs[p][kk][192 + tx * 4];
                const float br[16] = {y0.x, y0.y, y0.z, y0.w, y1.x, y1.y, y1.z, y1.w,
                                      y2.x, y2.y, y2.z, y2.w, y3.x, y3.y, y3.z, y3.w};
#pragma unroll
                for (int i = 0; i < 16; ++i) {
                    const float ar = f4c(av[i], t);
#pragma unroll
                    for (int j = 0; j < 16; ++j) acc[i][j] += ar * br[j];
                }
            }
        }
        __syncthreads();                 // drains vmcnt(0): next buffer's DMA complete
        if (has_next) p ^= 1;
    }
#undef STAGE

#pragma unroll
    for (int qi = 0; qi < 4; ++qi)
#pragma unroll
        for (int i = 0; i < 4; ++i) {
            int row = row0 + qi * 64 + ty * 4 + i;
#pragma unroll
            for (int qj = 0; qj < 4; ++qj) {
                int col = col0 + qj * 64 + tx * 4;
                float4 v;
                v.x = acc[qi * 4 + i][qj * 4 + 0] + bias[col + 0];
                v.y = acc[qi * 4 + i][qj * 4 + 1] + bias[col + 1];
                v.z = acc[qi * 4 + i][qj * 4 + 2] + bias[col + 2];
                v.w = acc[qi * 4 + i][qj * 4 + 3] + bias[col + 3];
                if (DO_RELU) {
                    v.x = fmaxf(v.x, 0.f); v.y = fmaxf(v.y, 0.f);
                    v.z = fmaxf(v.z, 0.f); v.w = fmaxf(v.w, 0.f);
                }
                *(float4*)(C + (size_t)row * N + col) = v;
            }
        }
}

// ---------------- fp32 GEMM (narrow, N=128 for the logits/reg head) ----------------
// Unchanged R2 kernel: 128x128 tile, 8x8 per thread (GEMM3 is only ~50 us).
__global__ __launch_bounds__(256) void gemm128(const float* __restrict__ A,
                                               const float* __restrict__ B,
                                               const float* __restrict__ bias,
                                               float* __restrict__ C,
                                               int K, int N, int do_relu) {
    __shared__ float As[2][BK][128];   // 16 KB
    __shared__ float Bs[2][BK][128];   // 16 KB
    const int tid  = threadIdx.x;
    const int row0 = blockIdx.x * 128;
    const int col0 = blockIdx.y * 128;
    const int tx = tid & 15, ty = tid >> 4;

    const int arow  = tid >> 1;
    const int akoff = (tid & 1) * 8;
    const int brow  = tid >> 5;
    const int bc4   = (tid & 31) * 4;

    const float* Ap = A + (size_t)(row0 + arow) * K + akoff;
    const float* Bp = B + col0 + bc4;

    float acc[8][8];
#pragma unroll
    for (int i = 0; i < 8; ++i)
#pragma unroll
        for (int j = 0; j < 8; ++j) acc[i][j] = 0.f;

    float4 a0 = *(const float4*)(Ap + 0);
    float4 a1 = *(const float4*)(Ap + 4);
    float4 b0 = *(const float4*)(Bp + (size_t)brow * N);
    float4 b1 = *(const float4*)(Bp + (size_t)(brow + 8) * N);
    As[0][akoff + 0][arow] = a0.x;
    As[0][akoff + 1][arow] = a0.y;
    As[0][akoff + 2][arow] = a0.z;
    As[0][akoff + 3][arow] = a0.w;
    As[0][akoff + 4][arow] = a1.x;
    As[0][akoff + 5][arow] = a1.y;
    As[0][akoff + 6][arow] = a1.z;
    As[0][akoff + 7][arow] = a1.w;
    *(float4*)&Bs[0][brow][bc4]     = b0;
    *(float4*)&Bs[0][brow + 8][bc4] = b1;
    __syncthreads();

    int p = 0;
    for (int k0 = 0; k0 < K; k0 += BK) {
        const bool has_next = (k0 + BK) < K;
        if (has_next) {
            a0 = *(const float4*)(Ap + k0 + BK);
            a1 = *(const float4*)(Ap + k0 + BK + 4);
            b0 = *(const float4*)(Bp + (size_t)(k0 + BK + brow) * N);
            b1 = *(const float4*)(Bp + (size_t)(k0 + BK + brow + 8) * N);
        }
#pragma unroll
        for (int kk = 0; kk < BK; ++kk) {
            float4 x0 = *(const float4*)&As[p][kk][ty * 4];
            float4 x1 = *(const float4*)&As[p][kk][64 + ty * 4];
            float4 y0 = *(const float4*)&Bs[p][kk][tx * 4];
            float4 y1 = *(const float4*)&Bs[p][kk][64 + tx * 4];
            float ar[8] = {x0.x, x0.y, x0.z, x0.w, x1.x, x1.y, x1.z, x1.w};
            float br[8] = {y0.x, y0.y, y0.z, y0.w, y1.x, y1.y, y1.z, y1.w};
#pragma unroll
            for (int i = 0; i < 8; ++i)
#pragma unroll
                for (int j = 0; j < 8; ++j) acc[i][j] += ar[i] * br[j];
        }
        if (has_next) {
            const int q = p ^ 1;
            As[q][akoff + 0][arow] = a0.x;
            As[q][akoff + 1][arow] = a0.y;
            As[q][akoff + 2][arow] = a0.z;
            As[q][akoff + 3][arow] = a0.w;
            As[q][akoff + 4][arow] = a1.x;
            As[q][akoff + 5][arow] = a1.y;
            As[q][akoff + 6][arow] = a1.z;
            As[q][akoff + 7][arow] = a1.w;
            *(float4*)&Bs[q][brow][bc4]     = b0;
            *(float4*)&Bs[q][brow + 8][bc4] = b1;
            __syncthreads();
            p = q;
        }
    }

#pragma unroll
    for (int qi = 0; qi < 2; ++qi)
#pragma unroll
        for (int i = 0; i < 4; ++i) {
            int row = row0 + qi * 64 + ty * 4 + i;
#pragma unroll
            for (int qj = 0; qj < 2; ++qj) {
                int col = col0 + qj * 64 + tx * 4;
                float4 v;
                v.x = acc[qi * 4 + i][qj * 4 + 0] + bias[col + 0];
                v.y = acc[qi * 4 + i][qj * 4 + 1] + bias[col + 1];
                v.z = acc[qi * 4 + i][qj * 4 + 2] + bias[col + 2];
                v.w = acc[qi * 4 + i][qj * 4 + 3] + bias[col + 3];
                if (do_relu) {
                    v.x = fmaxf(v.x, 0.f); v.y = fmaxf(v.y, 0.f);
                    v.z = fmaxf(v.z, 0.f); v.w = fmaxf(v.w, 0.f);
                }
                *(float4*)(C + (size_t)row * N + col) = v;
            }
        }
}

// ---------------- concat wc|wr into [512][128] (zero padded), same for bias ----------------
__global__ void concat_w(const float* __restrict__ wc, const float* __restrict__ bc,
                         const float* __restrict__ wr, const float* __restrict__ br,
                         float* __restrict__ wcat, float* __restrict__ bcat) {
    int gid = blockIdx.x * 256 + threadIdx.x;
    if (gid >= HDIM * LRLD) return;
    int k = gid >> 7, j = gid & 127;
    float v = 0.f;
    if (j < 11)       v = wc[k * 11 + j];
    else if (j < 110) v = wr[k * 99 + (j - 11)];
    wcat[gid] = v;
    if (k == 0) {
        float b = 0.f;
        if (j < 11)       b = bc[j];
        else if (j < 110) b = br[j - 11];
        bcat[j] = b;
    }
}

// ---------------- softmax + score histogram ----------------
__global__ __launch_bounds__(256) void softmax_hist(const float* __restrict__ logreg,
                                                    float* __restrict__ scores,
                                                    int* __restrict__ hist) {
    __shared__ int lh[NBINS];   // 32 KB
    const int t = threadIdx.x;
    for (int i = t; i < NBINS; i += 256) lh[i] = 0;
    __syncthreads();

    const int r = blockIdx.x * 256 + t;
    const float* lr = logreg + (size_t)r * LRLD;
    float4 v0 = *(const float4*)(lr);
    float4 v1 = *(const float4*)(lr + 4);
    float4 v2 = *(const float4*)(lr + 8);
    float l[NCLS] = {v0.x, v0.y, v0.z, v0.w, v1.x, v1.y, v1.z, v1.w, v2.x, v2.y, v2.z};
    float m = l[0];
#pragma unroll
    for (int j = 1; j < NCLS; ++j) m = fmaxf(m, l[j]);
    float e[NCLS]; float s = 0.f;
#pragma unroll
    for (int j = 0; j < NCLS; ++j) { e[j] = expf(l[j] - m); s += e[j]; }
#pragma unroll
    for (int c = 1; c < NCLS; ++c) {
        float p = e[c] / s;
        scores[(size_t)r * 10 + (c - 1)] = p;
        if (p > SCORE_T) {
            int bin = (int)(p * (float)NBINS);
            bin = min(max(bin, 0), NBINS - 1);
            atomicAdd(&lh[bin], 1);
        }
    }
    __syncthreads();
    const int b = (blockIdx.x * 256) >> 14;
    for (int i = t; i < NBINS; i += 256) {
        int c = lh[i];
        if (c) atomicAdd(&hist[b * NBINS + i], c);
    }
}

// ---------------- find histogram bin threshold covering top >= TGT ----------------
__global__ __launch_bounds__(1024) void select_tau(const int* __restrict__ hist,
                                                   int* __restrict__ taubin) {
    __shared__ int seg[1024];
    __shared__ int best;
    const int b = blockIdx.x, t = threadIdx.x;
    if (t == 0) best = 0;
    const int base = t * 8;
    int loc[8];
    int s = 0;
#pragma unroll
    for (int i = 7; i >= 0; --i) {       // loc[i] = hist[base+i] + ... + hist[base+7]
        s += hist[b * NBINS + base + i];
        loc[i] = s;
    }
    seg[t] = s;
    __syncthreads();
    // inclusive suffix scan over seg: seg[t] = sum seg_orig[t..1023]
    for (int off = 1; off < 1024; off <<= 1) {
        int v = (t + off < 1024) ? seg[t + off] : 0;
        __syncthreads();
        seg[t] += v;
        __syncthreads();
    }
    const int above = (t + 1 < 1024) ? seg[t + 1] : 0;
    int bmax = -1;
#pragma unroll
    for (int i = 0; i < 8; ++i) {
        if (loc[i] + above >= TGT) bmax = base + i;
    }
    if (bmax >= 0) atomicMax(&best, bmax);
    __syncthreads();
    if (t == 0) taubin[b] = best;
}

// ---------------- gather top candidates as sortable keys ----------------
__global__ void gather_cand(const float* __restrict__ scores,
                            const float* __restrict__ logreg,
                            const float* __restrict__ proposals,
                            const int* __restrict__ taubin,
                            int* __restrict__ gcount,
                            unsigned long long* __restrict__ gkeys) {
    int gid = blockIdx.x * 256 + threadIdx.x;
    if (gid >= NROWS * 10) return;
    int r  = gid / 10;
    int ci = gid - r * 10;          // class-1
    int b  = r >> 14;
    float p = scores[gid];
    int bin = (int)(p * (float)NBINS);
    bin = min(max(bin, 0), NBINS - 1);
    if (bin < taubin[b]) return;
    if (!(p > SCORE_T)) return;
    float x1, y1, x2, y2;
    decode4(proposals + (size_t)r * 9, logreg + (size_t)r * LRLD + 11 + (ci + 1) * 9,
            x1, y1, x2, y2);
    if (!((x2 - x1) >= 0.01f && (y2 - y1) >= 0.01f)) return;
    int pos = atomicAdd(&gcount[b], 1);
    if (pos < CAP) {
        unsigned int sb   = __float_as_uint(p);                 // p > 0 => order-preserving
        unsigned int cand = (unsigned)(r - b * NPROP) * 10u + (unsigned)ci;
        // ascending sort => score desc (inverted bits), then cand asc (argmax tie-break)
        gkeys[(size_t)b * CAP + pos] =
            ((unsigned long long)(0xFFFFFFFFu - sb) << 32) | (unsigned long long)cand;
    }
}

// ---------------- bitonic sort of candidate keys per frame ----------------
// Adaptive size S = next_pow2(gc) (entries >= gc are never read by nms_out).
__global__ __launch_bounds__(1024) void sort_cand(int* __restrict__ gcount,
                                                  unsigned long long* __restrict__ gkeys) {
    __shared__ unsigned long long sk[CAP];
    int b = blockIdx.x, tid = threadIdx.x;
    int gc = gcount[b]; if (gc > CAP) gc = CAP;
    int S = 1024;
    while (S < gc) S <<= 1;              // uniform per block
    for (int i = tid; i < S; i += 1024)
        sk[i] = (i < gc) ? gkeys[(size_t)b * CAP + i] : ~0ULL;
    __syncthreads();
    for (int k = 2; k <= S; k <<= 1) {
        for (int j = k >> 1; j > 0; j >>= 1) {
            for (int i = tid; i < S; i += 1024) {
                int ixj = i ^ j;
                if (ixj > i) {
                    bool up = ((i & k) == 0);
                    unsigned long long a = sk[i], c = sk[ixj];
                    if ((a > c) == up) { sk[i] = c; sk[ixj] = a; }
                }
            }
            __syncthreads();
        }
    }
    for (int i = tid; i < S; i += 1024)
        gkeys[(size_t)b * CAP + i] = sk[i];
    if (tid == 0 && gcount[b] > CAP) gcount[b] = CAP;
}

// ---------------- serial greedy NMS scan + output ----------------
#define NPRE 2048
__global__ __launch_bounds__(64) void nms_out(const unsigned long long* __restrict__ gkeys,
                                              const int* __restrict__ gcount,
                                              const float* __restrict__ scores,
                                              const float* __restrict__ logreg,
                                              const float* __restrict__ proposals,
                                              float* __restrict__ out) {
    int b = blockIdx.x, tid = threadIdx.x;
    __shared__ unsigned long long skeys[NPRE];
    __shared__ float kbox[KKEEP][4];
    __shared__ int   kcls[KKEEP];
    __shared__ int   kcand[KKEEP];
    __shared__ int   kcount;
    if (tid == 0) kcount = 0;
    int gc = min(gcount[b], CAP);
    for (int i = tid; i < NPRE; i += 64)
        if (i < gc) skeys[i] = gkeys[(size_t)b * CAP + i];
    __syncthreads();
    for (int ptr = 0; ptr < gc; ++ptr) {
        __syncthreads();
        int kc = kcount;
        if (kc >= KKEEP) break;
        unsigned long long key = (ptr < NPRE) ? skeys[ptr] : gkeys[(size_t)b * CAP + ptr];
        unsigned int cand = (unsigned int)(key & 0xFFFFFFFFULL);
        int n = cand / 10;
        int c = (int)(cand - n * 10) + 1;
        int r = b * NPROP + n;
        float x1, y1, x2, y2;
        decode4(proposals + (size_t)r * 9, logreg + (size_t)r * LRLD + 11 + c * 9,
                x1, y1, x2, y2);
        int sup = 0;
        for (int q = tid; q < kc; q += 64) {
            if (kcls[q] == c) {
                float xx1 = fmaxf(x1, kbox[q][0]);
                float yy1 = fmaxf(y1, kbox[q][1]);
                float xx2 = fminf(x2, kbox[q][2]);
                float yy2 = fminf(y2, kbox[q][3]);
                float inter = fmaxf(xx2 - xx1, 0.f) * fmaxf(yy2 - yy1, 0.f);
                float aa = (kbox[q][2] - kbox[q][0]) * (kbox[q][3] - kbox[q][1]);
                float ab = (x2 - x1) * (y2 - y1);
                float iou = inter / (aa + ab - inter + 1e-9f);
                if (iou > NMS_T) sup = 1;
            }
        }
        if (!__any(sup)) {
            if (tid == 0) {
                kbox[kc][0] = x1; kbox[kc][1] = y1; kbox[kc][2] = x2; kbox[kc][3] = y2;
                kcls[kc] = c; kcand[kc] = (int)cand; kcount = kc + 1;
            }
        }
    }
    __syncthreads();
    int kc = min(kcount, KKEEP);
    for (int k = tid; k < KKEEP; k += 64) {
        int cand = (k < kc) ? kcand[k] : 0;     // exhausted list => argmax of all -inf = idx 0
        int n = cand / 10;
        int c = cand - n * 10 + 1;
        int r = b * NPROP + n;
        const float* prop = proposals + (size_t)r * 9;
        const float* rg = logreg + (size_t)r * LRLD + 11 + c * 9;
        float x1, y1, x2, y2;
        decode4(prop, rg, x1, y1, x2, y2);
        float* ob = out + ((size_t)b * KKEEP + k) * 9;
        ob[0] = x1; ob[1] = y1; ob[2] = x2; ob[3] = y2;
#pragma unroll
        for (int j = 0; j < 5; ++j) ob[4 + j] = prop[4 + j] + rg[4 + j];
        out[NFRAMES * KKEEP * 9 + b * KKEEP + k] =
            (k < kc) ? scores[(size_t)r * 10 + (c - 1)] : 0.f;
        out[NFRAMES * KKEEP * 9 + NFRAMES * KKEEP + b * KKEEP + k] =
            (k < kc) ? (float)c : -1.0f;
    }
}

// ---------------- host launch ----------------
extern "C" void kernel_launch(void* const* d_in, const int* in_sizes, int n_in,
                              void* d_out, int out_size, void* d_ws, size_t ws_size,
                              hipStream_t stream) {
    (void)in_sizes; (void)n_in; (void)out_size;
    if (ws_size < WS_NEEDED) return;

    const float* x         = (const float*)d_in[0];
    const float* proposals = (const float*)d_in[1];
    const float* w1        = (const float*)d_in[2];
    const float* b1        = (const float*)d_in[3];
    const float* w2        = (const float*)d_in[4];
    const float* b2        = (const float*)d_in[5];
    const float* wc        = (const float*)d_in[6];
    const float* bc        = (const float*)d_in[7];
    const float* wr        = (const float*)d_in[8];
    const float* br        = (const float*)d_in[9];
    float* out = (float*)d_out;

    char* ws = (char*)d_ws;
    float* h1     = (float*)(ws + OFF_H1);
    float* h2     = (float*)(ws + OFF_H2);
    float* logreg = (float*)(ws + OFF_LR);
    float* wcat   = (float*)(ws + OFF_WCAT);
    float* bcat   = (float*)(ws + OFF_BCAT);
    float* scores = (float*)(ws + OFF_SCORES);
    int*   hist   = (int*)(ws + OFF_HIST);
    int*   gcount = (int*)(ws + OFF_GCNT);
    int*   taubin = (int*)(ws + OFF_TAU);
    unsigned long long* gkeys = (unsigned long long*)(ws + OFF_GKEYS);

    // zero hist + gcount + taubin (ws is poisoned before every call)
    hipMemsetAsync(hist, 0, (size_t)(NFRAMES * NBINS * 4 + 256), stream);

    concat_w<<<(HDIM * LRLD + 255) / 256, 256, 0, stream>>>(wc, bc, wr, br, wcat, bcat);

    gemm512g<DIN_, HDIM, 1><<<dim3(NROWS / 256, HDIM / 256), 256, 0, stream>>>(x,  w1, b1, h1);
    gemm512g<HDIM, HDIM, 1><<<dim3(NROWS / 256, HDIM / 256), 256, 0, stream>>>(h1, w2, b2, h2);
    gemm128<<<dim3(NROWS / 128, 1), 256, 0, stream>>>(h2, wcat, bcat, logreg, HDIM, LRLD, 0);

    softmax_hist<<<NROWS / 256, 256, 0, stream>>>(logreg, scores, hist);
    select_tau<<<NFRAMES, 1024, 0, stream>>>(hist, taubin);
    gather_cand<<<(NROWS * 10 + 255) / 256, 256, 0, stream>>>(scores, logreg, proposals,
                                                              taubin, gcount, gkeys);
    sort_cand<<<NFRAMES, 1024, 0, stream>>>(gcount, gkeys);
    nms_out<<<NFRAMES, 64, 0, stream>>>(gkeys, gcount, scores, logreg, proposals, out);
}

// Round 6
// 1034.286 us; speedup vs baseline: 1.6834x; 1.6834x over previous
//
#include <hip/hip_runtime.h>
#include <stdint.h>

// ---------------- problem constants ----------------
#define NFRAMES 2
#define NPROP   16384
#define NROWS   (NFRAMES * NPROP)        // 32768
#define DIN_    1024
#define HDIM    512
#define NCLS    11
#define LRLD    128                      // padded cols of [logits(11) | reg(99) | pad]
#define NBINS   8192
#define CAP     4096                     // gathered candidate capacity per frame
#define TGT     1024                     // target top-N for NMS scan
#define KKEEP   100
#define SCORE_T 0.05f
#define NMS_T   0.5f
#define CLIPV   4.135166556742356f       // log(1000/16)
#define BK      16

// ---------------- workspace layout (bytes) ----------------
#define OFF_H1      0ULL                           // 32768*512 f32
#define OFF_H2      67108864ULL                    // 32768*512 f32
#define OFF_LR      134217728ULL                   // 32768*128 f32
#define OFF_WCAT    150994944ULL                   // 512*128 f32
#define OFF_BCAT    151257088ULL                   // 128 f32 (padded)
#define OFF_SCORES  151258112ULL                   // 32768*10 f32
#define OFF_HIST    152568832ULL                   // 2*8192 i32
#define OFF_GCNT    152634368ULL                   // 2 i32
#define OFF_TAU     152634376ULL                   // 2 i32
#define OFF_GKEYS   152634624ULL                   // 2*4096 u64
#define WS_NEEDED   152700160ULL

// async global->LDS DMA, 16B per lane (dest = wave-uniform base + lane*16)
#define GLD16(gp, lp)                                                         \
    __builtin_amdgcn_global_load_lds(                                         \
        (const __attribute__((address_space(1))) void*)(gp),                  \
        (__attribute__((address_space(3))) void*)(lp), 16, 0, 0)

// compile-time float4 component select (folds to a direct register use)
__device__ __forceinline__ float f4c(const float4& v, int i) {
    return i == 0 ? v.x : (i == 1 ? v.y : (i == 2 ? v.z : v.w));
}

// ---------------- box decode (must match reference float ops) ----------------
__device__ __forceinline__ void decode4(const float* __restrict__ prop,
                                        const float* __restrict__ rg,
                                        float& x1, float& y1, float& x2, float& y2) {
    float w  = prop[2] - prop[0];
    float h  = prop[3] - prop[1];
    float cx = prop[0] + 0.5f * w;
    float cy = prop[1] + 0.5f * h;
    float dx = rg[0] / 10.0f;
    float dy = rg[1] / 10.0f;
    float dw = fminf(rg[2] / 5.0f, CLIPV);
    float dh = fminf(rg[3] / 5.0f, CLIPV);
    float pcx = dx * w + cx;
    float pcy = dy * h + cy;
    float pw  = expf(dw) * w;
    float ph  = expf(dh) * h;
    x1 = pcx - 0.5f * pw;
    y1 = pcy - 0.5f * ph;
    x2 = pcx + 0.5f * pw;
    y2 = pcy + 0.5f * ph;
}

// ---------------- fp32 GEMM: C[M,N] = act(A[M,K]@B[K,N] + bias) ----------------
// R8: the R2 champion structure (128x128 tile, 8x8/thread, col-major As, 2-buf,
// one barrier per K-step) with the measured waste removed:
//  - B staging via global_load_lds (row-major = lane-linear-perfect): kills B's
//    register staging + ds_write_b128s + address VALU. A keeps the reg path
//    (col-major transpose can't DMA).
//  - no ar[]/br[] intermediate arrays: FMAs index float4 components directly
//    (R2's 423us @ 67.6% VALU had ~67us of non-FMA VALU; the array movs were
//    ~25% of VALU issue).
// Ceiling context (R1-R7): VALU=2rc vs LDS=12(r+c) cyc/wave/kk forces 67% for
// 8x8; 8x16/16x8 (89% ceiling) ran WORSE (compiler won't pipeline at >128-acc
// pressure: R4 54%, R6 58%); 16x16 dies on the 256-VGPR encoding limit (R7:
// AGPR-move thrash at 79% busy / 22% useful). 8x8 is the only config that
// ACHIEVES its ceiling; this round lowers its overhead, not its ceiling.
// FMA order per output unchanged (kk ascending) => bitwise-identical results.
template<int K, int N, int DO_RELU>
__global__ __launch_bounds__(256) void gemm128d(const float* __restrict__ A,
                                                const float* __restrict__ B,
                                                const float* __restrict__ bias,
                                                float* __restrict__ C) {
    __shared__ float As[2][BK][128];   // 16 KB, col-major (As[kk][m])
    __shared__ float Bs[2][BK][128];   // 16 KB, row-major (Bs[kk][n])
    const int tid  = threadIdx.x;
    const int w    = tid >> 6;          // wave 0..3
    const int lane = tid & 63;
    const int row0 = blockIdx.x * 128;
    const int col0 = blockIdx.y * 128;
    const int tx = tid & 15, ty = tid >> 4;

    // A staging (register path): thread -> row (tid>>1), 8 K-floats at (tid&1)*8
    const int arow  = tid >> 1;
    const int akoff = (tid & 1) * 8;
    const float* Ap = A + (size_t)(row0 + arow) * K + akoff;

    // B staging via DMA: wave w covers k-rows w*4..w*4+3 in 2 insts of 2 rows each.
    // inst j: dest &Bs[buf][w*4+j*2][0] (+lane*16 implicit); source row += lane>>5.
    const int brow0 = w * 4 + (lane >> 5);
    const float* Bp = B + col0 + ((lane & 31) << 2);

    float acc[8][8];
#pragma unroll
    for (int i = 0; i < 8; ++i)
#pragma unroll
        for (int j = 0; j < 8; ++j) acc[i][j] = 0.f;

    // prologue: tile 0
    float4 a0 = *(const float4*)(Ap + 0);
    float4 a1 = *(const float4*)(Ap + 4);
    GLD16(Bp + (size_t)(brow0 + 0) * N, &Bs[0][w * 4 + 0][0]);
    GLD16(Bp + (size_t)(brow0 + 2) * N, &Bs[0][w * 4 + 2][0]);
    As[0][akoff + 0][arow] = a0.x;
    As[0][akoff + 1][arow] = a0.y;
    As[0][akoff + 2][arow] = a0.z;
    As[0][akoff + 3][arow] = a0.w;
    As[0][akoff + 4][arow] = a1.x;
    As[0][akoff + 5][arow] = a1.y;
    As[0][akoff + 6][arow] = a1.z;
    As[0][akoff + 7][arow] = a1.w;
    __syncthreads();                    // drains vmcnt(0) + lgkmcnt(0)

    int p = 0;
    for (int k0 = 0; k0 < K; k0 += BK) {
        const bool has_next = (k0 + BK) < K;
        if (has_next) {
            // A: global->reg prefetch (consumed after the 1024-FMA stage)
            a0 = *(const float4*)(Ap + k0 + BK);
            a1 = *(const float4*)(Ap + k0 + BK + 4);
            // B: DMA straight into the buffer whose reads finished before the
            // PREVIOUS barrier; lands before the NEXT barrier's vmcnt drain.
            const int q = p ^ 1;
            GLD16(Bp + (size_t)(k0 + BK + brow0 + 0) * N, &Bs[q][w * 4 + 0][0]);
            GLD16(Bp + (size_t)(k0 + BK + brow0 + 2) * N, &Bs[q][w * 4 + 2][0]);
        }
#pragma unroll
        for (int kk = 0; kk < BK; ++kk) {
            float4 x0 = *(const float4*)&As[p][kk][ty * 4];
            float4 x1 = *(const float4*)&As[p][kk][64 + ty * 4];
            float4 y0 = *(const float4*)&Bs[p][kk][tx * 4];
            float4 y1 = *(const float4*)&Bs[p][kk][64 + tx * 4];
#pragma unroll
            for (int i = 0; i < 8; ++i) {
                const float ar = (i < 4) ? f4c(x0, i & 3) : f4c(x1, i & 3);
#pragma unroll
                for (int j = 0; j < 8; ++j) {
                    const float br = (j < 4) ? f4c(y0, j & 3) : f4c(y1, j & 3);
                    acc[i][j] += ar * br;
                }
            }
        }
        if (has_next) {
            const int q = p ^ 1;
            As[q][akoff + 0][arow] = a0.x;
            As[q][akoff + 1][arow] = a0.y;
            As[q][akoff + 2][arow] = a0.z;
            As[q][akoff + 3][arow] = a0.w;
            As[q][akoff + 4][arow] = a1.x;
            As[q][akoff + 5][arow] = a1.y;
            As[q][akoff + 6][arow] = a1.z;
            As[q][akoff + 7][arow] = a1.w;
            __syncthreads();
            p = q;
        }
    }

#pragma unroll
    for (int qi = 0; qi < 2; ++qi)
#pragma unroll
        for (int i = 0; i < 4; ++i) {
            int row = row0 + qi * 64 + ty * 4 + i;
#pragma unroll
            for (int qj = 0; qj < 2; ++qj) {
                int col = col0 + qj * 64 + tx * 4;
                float4 v;
                v.x = acc[qi * 4 + i][qj * 4 + 0] + bias[col + 0];
                v.y = acc[qi * 4 + i][qj * 4 + 1] + bias[col + 1];
                v.z = acc[qi * 4 + i][qj * 4 + 2] + bias[col + 2];
                v.w = acc[qi * 4 + i][qj * 4 + 3] + bias[col + 3];
                if (DO_RELU) {
                    v.x = fmaxf(v.x, 0.f); v.y = fmaxf(v.y, 0.f);
                    v.z = fmaxf(v.z, 0.f); v.w = fmaxf(v.w, 0.f);
                }
                *(float4*)(C + (size_t)row * N + col) = v;
            }
        }
}

// ---------------- concat wc|wr into [512][128] (zero padded), same for bias ----------------
__global__ void concat_w(const float* __restrict__ wc, const float* __restrict__ bc,
                         const float* __restrict__ wr, const float* __restrict__ br,
                         float* __restrict__ wcat, float* __restrict__ bcat) {
    int gid = blockIdx.x * 256 + threadIdx.x;
    if (gid >= HDIM * LRLD) return;
    int k = gid >> 7, j = gid & 127;
    float v = 0.f;
    if (j < 11)       v = wc[k * 11 + j];
    else if (j < 110) v = wr[k * 99 + (j - 11)];
    wcat[gid] = v;
    if (k == 0) {
        float b = 0.f;
        if (j < 11)       b = bc[j];
        else if (j < 110) b = br[j - 11];
        bcat[j] = b;
    }
}

// ---------------- softmax + score histogram ----------------
__global__ __launch_bounds__(256) void softmax_hist(const float* __restrict__ logreg,
                                                    float* __restrict__ scores,
                                                    int* __restrict__ hist) {
    __shared__ int lh[NBINS];   // 32 KB
    const int t = threadIdx.x;
    for (int i = t; i < NBINS; i += 256) lh[i] = 0;
    __syncthreads();

    const int r = blockIdx.x * 256 + t;
    const float* lr = logreg + (size_t)r * LRLD;
    float4 v0 = *(const float4*)(lr);
    float4 v1 = *(const float4*)(lr + 4);
    float4 v2 = *(const float4*)(lr + 8);
    float l[NCLS] = {v0.x, v0.y, v0.z, v0.w, v1.x, v1.y, v1.z, v1.w, v2.x, v2.y, v2.z};
    float m = l[0];
#pragma unroll
    for (int j = 1; j < NCLS; ++j) m = fmaxf(m, l[j]);
    float e[NCLS]; float s = 0.f;
#pragma unroll
    for (int j = 0; j < NCLS; ++j) { e[j] = expf(l[j] - m); s += e[j]; }
#pragma unroll
    for (int c = 1; c < NCLS; ++c) {
        float p = e[c] / s;
        scores[(size_t)r * 10 + (c - 1)] = p;
        if (p > SCORE_T) {
            int bin = (int)(p * (float)NBINS);
            bin = min(max(bin, 0), NBINS - 1);
            atomicAdd(&lh[bin], 1);
        }
    }
    __syncthreads();
    const int b = (blockIdx.x * 256) >> 14;
    for (int i = t; i < NBINS; i += 256) {
        int c = lh[i];
        if (c) atomicAdd(&hist[b * NBINS + i], c);
    }
}

// ---------------- find histogram bin threshold covering top >= TGT ----------------
__global__ __launch_bounds__(1024) void select_tau(const int* __restrict__ hist,
                                                   int* __restrict__ taubin) {
    __shared__ int seg[1024];
    __shared__ int best;
    const int b = blockIdx.x, t = threadIdx.x;
    if (t == 0) best = 0;
    const int base = t * 8;
    int loc[8];
    int s = 0;
#pragma unroll
    for (int i = 7; i >= 0; --i) {       // loc[i] = hist[base+i] + ... + hist[base+7]
        s += hist[b * NBINS + base + i];
        loc[i] = s;
    }
    seg[t] = s;
    __syncthreads();
    // inclusive suffix scan over seg: seg[t] = sum seg_orig[t..1023]
    for (int off = 1; off < 1024; off <<= 1) {
        int v = (t + off < 1024) ? seg[t + off] : 0;
        __syncthreads();
        seg[t] += v;
        __syncthreads();
    }
    const int above = (t + 1 < 1024) ? seg[t + 1] : 0;
    int bmax = -1;
#pragma unroll
    for (int i = 0; i < 8; ++i) {
        if (loc[i] + above >= TGT) bmax = base + i;
    }
    if (bmax >= 0) atomicMax(&best, bmax);
    __syncthreads();
    if (t == 0) taubin[b] = best;
}

// ---------------- gather top candidates as sortable keys ----------------
__global__ void gather_cand(const float* __restrict__ scores,
                            const float* __restrict__ logreg,
                            const float* __restrict__ proposals,
                            const int* __restrict__ taubin,
                            int* __restrict__ gcount,
                            unsigned long long* __restrict__ gkeys) {
    int gid = blockIdx.x * 256 + threadIdx.x;
    if (gid >= NROWS * 10) return;
    int r  = gid / 10;
    int ci = gid - r * 10;          // class-1
    int b  = r >> 14;
    float p = scores[gid];
    int bin = (int)(p * (float)NBINS);
    bin = min(max(bin, 0), NBINS - 1);
    if (bin < taubin[b]) return;
    if (!(p > SCORE_T)) return;
    float x1, y1, x2, y2;
    decode4(proposals + (size_t)r * 9, logreg + (size_t)r * LRLD + 11 + (ci + 1) * 9,
            x1, y1, x2, y2);
    if (!((x2 - x1) >= 0.01f && (y2 - y1) >= 0.01f)) return;
    int pos = atomicAdd(&gcount[b], 1);
    if (pos < CAP) {
        unsigned int sb   = __float_as_uint(p);                 // p > 0 => order-preserving
        unsigned int cand = (unsigned)(r - b * NPROP) * 10u + (unsigned)ci;
        // ascending sort => score desc (inverted bits), then cand asc (argmax tie-break)
        gkeys[(size_t)b * CAP + pos] =
            ((unsigned long long)(0xFFFFFFFFu - sb) << 32) | (unsigned long long)cand;
    }
}

// ---------------- bitonic sort of candidate keys per frame ----------------
// Adaptive size S = next_pow2(gc) (entries >= gc are never read by nms_out).
__global__ __launch_bounds__(1024) void sort_cand(int* __restrict__ gcount,
                                                  unsigned long long* __restrict__ gkeys) {
    __shared__ unsigned long long sk[CAP];
    int b = blockIdx.x, tid = threadIdx.x;
    int gc = gcount[b]; if (gc > CAP) gc = CAP;
    int S = 1024;
    while (S < gc) S <<= 1;              // uniform per block
    for (int i = tid; i < S; i += 1024)
        sk[i] = (i < gc) ? gkeys[(size_t)b * CAP + i] : ~0ULL;
    __syncthreads();
    for (int k = 2; k <= S; k <<= 1) {
        for (int j = k >> 1; j > 0; j >>= 1) {
            for (int i = tid; i < S; i += 1024) {
                int ixj = i ^ j;
                if (ixj > i) {
                    bool up = ((i & k) == 0);
                    unsigned long long a = sk[i], c = sk[ixj];
                    if ((a > c) == up) { sk[i] = c; sk[ixj] = a; }
                }
            }
            __syncthreads();
        }
    }
    for (int i = tid; i < S; i += 1024)
        gkeys[(size_t)b * CAP + i] = sk[i];
    if (tid == 0 && gcount[b] > CAP) gcount[b] = CAP;
}

// ---------------- serial greedy NMS scan + output ----------------
#define NPRE 2048
__global__ __launch_bounds__(64) void nms_out(const unsigned long long* __restrict__ gkeys,
                                              const int* __restrict__ gcount,
                                              const float* __restrict__ scores,
                                              const float* __restrict__ logreg,
                                              const float* __restrict__ proposals,
                                              float* __restrict__ out) {
    int b = blockIdx.x, tid = threadIdx.x;
    __shared__ unsigned long long skeys[NPRE];
    __shared__ float kbox[KKEEP][4];
    __shared__ int   kcls[KKEEP];
    __shared__ int   kcand[KKEEP];
    __shared__ int   kcount;
    if (tid == 0) kcount = 0;
    int gc = min(gcount[b], CAP);
    for (int i = tid; i < NPRE; i += 64)
        if (i < gc) skeys[i] = gkeys[(size_t)b * CAP + i];
    __syncthreads();
    for (int ptr = 0; ptr < gc; ++ptr) {
        __syncthreads();
        int kc = kcount;
        if (kc >= KKEEP) break;
        unsigned long long key = (ptr < NPRE) ? skeys[ptr] : gkeys[(size_t)b * CAP + ptr];
        unsigned int cand = (unsigned int)(key & 0xFFFFFFFFULL);
        int n = cand / 10;
        int c = (int)(cand - n * 10) + 1;
        int r = b * NPROP + n;
        float x1, y1, x2, y2;
        decode4(proposals + (size_t)r * 9, logreg + (size_t)r * LRLD + 11 + c * 9,
                x1, y1, x2, y2);
        int sup = 0;
        for (int q = tid; q < kc; q += 64) {
            if (kcls[q] == c) {
                float xx1 = fmaxf(x1, kbox[q][0]);
                float yy1 = fmaxf(y1, kbox[q][1]);
                float xx2 = fminf(x2, kbox[q][2]);
                float yy2 = fminf(y2, kbox[q][3]);
                float inter = fmaxf(xx2 - xx1, 0.f) * fmaxf(yy2 - yy1, 0.f);
                float aa = (kbox[q][2] - kbox[q][0]) * (kbox[q][3] - kbox[q][1]);
                float ab = (x2 - x1) * (y2 - y1);
                float iou = inter / (aa + ab - inter + 1e-9f);
                if (iou > NMS_T) sup = 1;
            }
        }
        if (!__any(sup)) {
            if (tid == 0) {
                kbox[kc][0] = x1; kbox[kc][1] = y1; kbox[kc][2] = x2; kbox[kc][3] = y2;
                kcls[kc] = c; kcand[kc] = (int)cand; kcount = kc + 1;
            }
        }
    }
    __syncthreads();
    int kc = min(kcount, KKEEP);
    for (int k = tid; k < KKEEP; k += 64) {
        int cand = (k < kc) ? kcand[k] : 0;     // exhausted list => argmax of all -inf = idx 0
        int n = cand / 10;
        int c = cand - n * 10 + 1;
        int r = b * NPROP + n;
        const float* prop = proposals + (size_t)r * 9;
        const float* rg = logreg + (size_t)r * LRLD + 11 + c * 9;
        float x1, y1, x2, y2;
        decode4(prop, rg, x1, y1, x2, y2);
        float* ob = out + ((size_t)b * KKEEP + k) * 9;
        ob[0] = x1; ob[1] = y1; ob[2] = x2; ob[3] = y2;
#pragma unroll
        for (int j = 0; j < 5; ++j) ob[4 + j] = prop[4 + j] + rg[4 + j];
        out[NFRAMES * KKEEP * 9 + b * KKEEP + k] =
            (k < kc) ? scores[(size_t)r * 10 + (c - 1)] : 0.f;
        out[NFRAMES * KKEEP * 9 + NFRAMES * KKEEP + b * KKEEP + k] =
            (k < kc) ? (float)c : -1.0f;
    }
}

// ---------------- host launch ----------------
extern "C" void kernel_launch(void* const* d_in, const int* in_sizes, int n_in,
                              void* d_out, int out_size, void* d_ws, size_t ws_size,
                              hipStream_t stream) {
    (void)in_sizes; (void)n_in; (void)out_size;
    if (ws_size < WS_NEEDED) return;

    const float* x         = (const float*)d_in[0];
    const float* proposals = (const float*)d_in[1];
    const float* w1        = (const float*)d_in[2];
    const float* b1        = (const float*)d_in[3];
    const float* w2        = (const float*)d_in[4];
    const float* b2        = (const float*)d_in[5];
    const float* wc        = (const float*)d_in[6];
    const float* bc        = (const float*)d_in[7];
    const float* wr        = (const float*)d_in[8];
    const float* br        = (const float*)d_in[9];
    float* out = (float*)d_out;

    char* ws = (char*)d_ws;
    float* h1     = (float*)(ws + OFF_H1);
    float* h2     = (float*)(ws + OFF_H2);
    float* logreg = (float*)(ws + OFF_LR);
    float* wcat   = (float*)(ws + OFF_WCAT);
    float* bcat   = (float*)(ws + OFF_BCAT);
    float* scores = (float*)(ws + OFF_SCORES);
    int*   hist   = (int*)(ws + OFF_HIST);
    int*   gcount = (int*)(ws + OFF_GCNT);
    int*   taubin = (int*)(ws + OFF_TAU);
    unsigned long long* gkeys = (unsigned long long*)(ws + OFF_GKEYS);

    // zero hist + gcount + taubin (ws is poisoned before every call)
    hipMemsetAsync(hist, 0, (size_t)(NFRAMES * NBINS * 4 + 256), stream);

    concat_w<<<(HDIM * LRLD + 255) / 256, 256, 0, stream>>>(wc, bc, wr, br, wcat, bcat);

    gemm128d<DIN_, HDIM, 1><<<dim3(NROWS / 128, HDIM / 128), 256, 0, stream>>>(x,  w1, b1, h1);
    gemm128d<HDIM, HDIM, 1><<<dim3(NROWS / 128, HDIM / 128), 256, 0, stream>>>(h1, w2, b2, h2);
    gemm128d<HDIM, LRLD, 0><<<dim3(NROWS / 128, 1),          256, 0, stream>>>(h2, wcat, bcat, logreg);

    softmax_hist<<<NROWS / 256, 256, 0, stream>>>(logreg, scores, hist);
    select_tau<<<NFRAMES, 1024, 0, stream>>>(hist, taubin);
    gather_cand<<<(NROWS * 10 + 255) / 256, 256, 0, stream>>>(scores, logreg, proposals,
                                                              taubin, gcount, gkeys);
    sort_cand<<<NFRAMES, 1024, 0, stream>>>(gcount, gkeys);
    nms_out<<<NFRAMES, 64, 0, stream>>>(gkeys, gcount, scores, logreg, proposals, out);
}

// Round 7
// 941.690 us; speedup vs baseline: 1.8490x; 1.0983x over previous
//
#include <hip/hip_runtime.h>
#include <stdint.h>

// ---------------- problem constants ----------------
#define NFRAMES 2
#define NPROP   16384
#define NROWS   (NFRAMES * NPROP)        // 32768
#define DIN_    1024
#define HDIM    512
#define NCLS    11
#define LRLD    128                      // padded cols of [logits(11) | reg(99) | pad]
#define NBINS   8192
#define CAP     4096                     // gathered candidate capacity per frame
#define TGT     1024                     // target top-N for NMS scan
#define KKEEP   100
#define SCORE_T 0.05f
#define NMS_T   0.5f
#define CLIPV   4.135166556742356f       // log(1000/16)
#define BK      16

// ---------------- workspace layout (bytes) ----------------
#define OFF_H1      0ULL                           // 32768*512 f32
#define OFF_H2      67108864ULL                    // 32768*512 f32
#define OFF_LR      134217728ULL                   // 32768*128 f32
#define OFF_WCAT    150994944ULL                   // 512*128 f32
#define OFF_BCAT    151257088ULL                   // 128 f32 (padded)
#define OFF_SCORES  151258112ULL                   // 32768*10 f32
#define OFF_HIST    152568832ULL                   // 2*8192 i32
#define OFF_GCNT    152634368ULL                   // 2 i32
#define OFF_TAU     152634376ULL                   // 2 i32
#define OFF_GKEYS   152634624ULL                   // 2*4096 u64
#define WS_NEEDED   152700160ULL

// ---------------- box decode (must match reference float ops) ----------------
__device__ __forceinline__ void decode4(const float* __restrict__ prop,
                                        const float* __restrict__ rg,
                                        float& x1, float& y1, float& x2, float& y2) {
    float w  = prop[2] - prop[0];
    float h  = prop[3] - prop[1];
    float cx = prop[0] + 0.5f * w;
    float cy = prop[1] + 0.5f * h;
    float dx = rg[0] / 10.0f;
    float dy = rg[1] / 10.0f;
    float dw = fminf(rg[2] / 5.0f, CLIPV);
    float dh = fminf(rg[3] / 5.0f, CLIPV);
    float pcx = dx * w + cx;
    float pcy = dy * h + cy;
    float pw  = expf(dw) * w;
    float ph  = expf(dh) * h;
    x1 = pcx - 0.5f * pw;
    y1 = pcy - 0.5f * ph;
    x2 = pcx + 0.5f * pw;
    y2 = pcy + 0.5f * ph;
}

// ---------------- fp32 GEMM: C[M,N] = act(A[M,K]@B[K,N] + bias) ----------------
// FROZEN at the R2 champion source (423 us GEMM1, VALU 67.6% = its exact
// LDS-pipe model ceiling: per kk, VALU 128 cyc/SIMD vs LDS 192 cyc/CU).
// R3-R8 post-mortems: every perturbation regressed 13-130% --
//   8x16 tile (89% ceiling): compiler allocates <=170 VGPR, serializes reads
//     (R4 536us/54%, R6 636us/58%); explicit reg ping-pong flattened (R5 550us);
//   16x16: 256-VGPR encoding wall -> accvgpr thrash (R7 977us, 79% busy/22% useful);
//   DMA-B + direct float4 indexing: VGPR 80, accvgpr moves +100us VALU (R8 476us).
// This compiler's codegen for THIS source is a verified local optimum. Do not touch.
__global__ __launch_bounds__(256) void gemm128(const float* __restrict__ A,
                                               const float* __restrict__ B,
                                               const float* __restrict__ bias,
                                               float* __restrict__ C,
                                               int K, int N, int do_relu) {
    __shared__ float As[2][BK][128];   // 16 KB
    __shared__ float Bs[2][BK][128];   // 16 KB
    const int tid  = threadIdx.x;
    const int row0 = blockIdx.x * 128;
    const int col0 = blockIdx.y * 128;
    const int tx = tid & 15, ty = tid >> 4;

    // A staging: thread -> row (tid>>1), 8 consecutive K floats at (tid&1)*8
    const int arow  = tid >> 1;
    const int akoff = (tid & 1) * 8;
    // B staging: thread -> rows (tid>>5) and (tid>>5)+8, float4 col (tid&31)*4
    const int brow  = tid >> 5;
    const int bc4   = (tid & 31) * 4;

    const float* Ap = A + (size_t)(row0 + arow) * K + akoff;
    const float* Bp = B + col0 + bc4;

    float acc[8][8];
#pragma unroll
    for (int i = 0; i < 8; ++i)
#pragma unroll
        for (int j = 0; j < 8; ++j) acc[i][j] = 0.f;

    // prologue: load tile 0 into regs, write LDS[0]
    float4 a0 = *(const float4*)(Ap + 0);
    float4 a1 = *(const float4*)(Ap + 4);
    float4 b0 = *(const float4*)(Bp + (size_t)brow * N);
    float4 b1 = *(const float4*)(Bp + (size_t)(brow + 8) * N);
    As[0][akoff + 0][arow] = a0.x;
    As[0][akoff + 1][arow] = a0.y;
    As[0][akoff + 2][arow] = a0.z;
    As[0][akoff + 3][arow] = a0.w;
    As[0][akoff + 4][arow] = a1.x;
    As[0][akoff + 5][arow] = a1.y;
    As[0][akoff + 6][arow] = a1.z;
    As[0][akoff + 7][arow] = a1.w;
    *(float4*)&Bs[0][brow][bc4]     = b0;
    *(float4*)&Bs[0][brow + 8][bc4] = b1;
    __syncthreads();

    int p = 0;
    for (int k0 = 0; k0 < K; k0 += BK) {
        const bool has_next = (k0 + BK) < K;
        if (has_next) {   // prefetch next tile into regs; consumed after 16*64 FMAs
            a0 = *(const float4*)(Ap + k0 + BK);
            a1 = *(const float4*)(Ap + k0 + BK + 4);
            b0 = *(const float4*)(Bp + (size_t)(k0 + BK + brow) * N);
            b1 = *(const float4*)(Bp + (size_t)(k0 + BK + brow + 8) * N);
        }
#pragma unroll
        for (int kk = 0; kk < BK; ++kk) {
            float4 x0 = *(const float4*)&As[p][kk][ty * 4];
            float4 x1 = *(const float4*)&As[p][kk][64 + ty * 4];
            float4 y0 = *(const float4*)&Bs[p][kk][tx * 4];
            float4 y1 = *(const float4*)&Bs[p][kk][64 + tx * 4];
            float ar[8] = {x0.x, x0.y, x0.z, x0.w, x1.x, x1.y, x1.z, x1.w};
            float br[8] = {y0.x, y0.y, y0.z, y0.w, y1.x, y1.y, y1.z, y1.w};
#pragma unroll
            for (int i = 0; i < 8; ++i)
#pragma unroll
                for (int j = 0; j < 8; ++j) acc[i][j] += ar[i] * br[j];
        }
        if (has_next) {
            const int q = p ^ 1;   // writes target the buffer whose reads finished
            As[q][akoff + 0][arow] = a0.x;   // before the PREVIOUS barrier
            As[q][akoff + 1][arow] = a0.y;
            As[q][akoff + 2][arow] = a0.z;
            As[q][akoff + 3][arow] = a0.w;
            As[q][akoff + 4][arow] = a1.x;
            As[q][akoff + 5][arow] = a1.y;
            As[q][akoff + 6][arow] = a1.z;
            As[q][akoff + 7][arow] = a1.w;
            *(float4*)&Bs[q][brow][bc4]     = b0;
            *(float4*)&Bs[q][brow + 8][bc4] = b1;
            __syncthreads();
            p = q;
        }
    }

#pragma unroll
    for (int qi = 0; qi < 2; ++qi)
#pragma unroll
        for (int i = 0; i < 4; ++i) {
            int row = row0 + qi * 64 + ty * 4 + i;
#pragma unroll
            for (int qj = 0; qj < 2; ++qj) {
                int col = col0 + qj * 64 + tx * 4;
                float4 v;
                v.x = acc[qi * 4 + i][qj * 4 + 0] + bias[col + 0];
                v.y = acc[qi * 4 + i][qj * 4 + 1] + bias[col + 1];
                v.z = acc[qi * 4 + i][qj * 4 + 2] + bias[col + 2];
                v.w = acc[qi * 4 + i][qj * 4 + 3] + bias[col + 3];
                if (do_relu) {
                    v.x = fmaxf(v.x, 0.f); v.y = fmaxf(v.y, 0.f);
                    v.z = fmaxf(v.z, 0.f); v.w = fmaxf(v.w, 0.f);
                }
                *(float4*)(C + (size_t)row * N + col) = v;
            }
        }
}

// ---------------- concat wc|wr into [512][128] (zero padded), same for bias ----------------
__global__ void concat_w(const float* __restrict__ wc, const float* __restrict__ bc,
                         const float* __restrict__ wr, const float* __restrict__ br,
                         float* __restrict__ wcat, float* __restrict__ bcat) {
    int gid = blockIdx.x * 256 + threadIdx.x;
    if (gid >= HDIM * LRLD) return;
    int k = gid >> 7, j = gid & 127;
    float v = 0.f;
    if (j < 11)       v = wc[k * 11 + j];
    else if (j < 110) v = wr[k * 99 + (j - 11)];
    wcat[gid] = v;
    if (k == 0) {
        float b = 0.f;
        if (j < 11)       b = bc[j];
        else if (j < 110) b = br[j - 11];
        bcat[j] = b;
    }
}

// ---------------- softmax + score histogram ----------------
__global__ __launch_bounds__(256) void softmax_hist(const float* __restrict__ logreg,
                                                    float* __restrict__ scores,
                                                    int* __restrict__ hist) {
    __shared__ int lh[NBINS];   // 32 KB
    const int t = threadIdx.x;
    for (int i = t; i < NBINS; i += 256) lh[i] = 0;
    __syncthreads();

    const int r = blockIdx.x * 256 + t;
    const float* lr = logreg + (size_t)r * LRLD;
    float4 v0 = *(const float4*)(lr);
    float4 v1 = *(const float4*)(lr + 4);
    float4 v2 = *(const float4*)(lr + 8);
    float l[NCLS] = {v0.x, v0.y, v0.z, v0.w, v1.x, v1.y, v1.z, v1.w, v2.x, v2.y, v2.z};
    float m = l[0];
#pragma unroll
    for (int j = 1; j < NCLS; ++j) m = fmaxf(m, l[j]);
    float e[NCLS]; float s = 0.f;
#pragma unroll
    for (int j = 0; j < NCLS; ++j) { e[j] = expf(l[j] - m); s += e[j]; }
#pragma unroll
    for (int c = 1; c < NCLS; ++c) {
        float p = e[c] / s;
        scores[(size_t)r * 10 + (c - 1)] = p;
        if (p > SCORE_T) {
            int bin = (int)(p * (float)NBINS);
            bin = min(max(bin, 0), NBINS - 1);
            atomicAdd(&lh[bin], 1);
        }
    }
    __syncthreads();
    const int b = (blockIdx.x * 256) >> 14;
    for (int i = t; i < NBINS; i += 256) {
        int c = lh[i];
        if (c) atomicAdd(&hist[b * NBINS + i], c);
    }
}

// ---------------- find histogram bin threshold covering top >= TGT ----------------
__global__ __launch_bounds__(1024) void select_tau(const int* __restrict__ hist,
                                                   int* __restrict__ taubin) {
    __shared__ int seg[1024];
    __shared__ int best;
    const int b = blockIdx.x, t = threadIdx.x;
    if (t == 0) best = 0;
    const int base = t * 8;
    int loc[8];
    int s = 0;
#pragma unroll
    for (int i = 7; i >= 0; --i) {       // loc[i] = hist[base+i] + ... + hist[base+7]
        s += hist[b * NBINS + base + i];
        loc[i] = s;
    }
    seg[t] = s;
    __syncthreads();
    // inclusive suffix scan over seg: seg[t] = sum seg_orig[t..1023]
    for (int off = 1; off < 1024; off <<= 1) {
        int v = (t + off < 1024) ? seg[t + off] : 0;
        __syncthreads();
        seg[t] += v;
        __syncthreads();
    }
    const int above = (t + 1 < 1024) ? seg[t + 1] : 0;
    int bmax = -1;
#pragma unroll
    for (int i = 0; i < 8; ++i) {
        if (loc[i] + above >= TGT) bmax = base + i;
    }
    if (bmax >= 0) atomicMax(&best, bmax);
    __syncthreads();
    if (t == 0) taubin[b] = best;
}

// ---------------- gather top candidates as sortable keys ----------------
__global__ void gather_cand(const float* __restrict__ scores,
                            const float* __restrict__ logreg,
                            const float* __restrict__ proposals,
                            const int* __restrict__ taubin,
                            int* __restrict__ gcount,
                            unsigned long long* __restrict__ gkeys) {
    int gid = blockIdx.x * 256 + threadIdx.x;
    if (gid >= NROWS * 10) return;
    int r  = gid / 10;
    int ci = gid - r * 10;          // class-1
    int b  = r >> 14;
    float p = scores[gid];
    int bin = (int)(p * (float)NBINS);
    bin = min(max(bin, 0), NBINS - 1);
    if (bin < taubin[b]) return;
    if (!(p > SCORE_T)) return;
    float x1, y1, x2, y2;
    decode4(proposals + (size_t)r * 9, logreg + (size_t)r * LRLD + 11 + (ci + 1) * 9,
            x1, y1, x2, y2);
    if (!((x2 - x1) >= 0.01f && (y2 - y1) >= 0.01f)) return;
    int pos = atomicAdd(&gcount[b], 1);
    if (pos < CAP) {
        unsigned int sb   = __float_as_uint(p);                 // p > 0 => order-preserving
        unsigned int cand = (unsigned)(r - b * NPROP) * 10u + (unsigned)ci;
        // ascending sort => score desc (inverted bits), then cand asc (argmax tie-break)
        gkeys[(size_t)b * CAP + pos] =
            ((unsigned long long)(0xFFFFFFFFu - sb) << 32) | (unsigned long long)cand;
    }
}

// ---------------- bitonic sort of candidate keys per frame ----------------
// Adaptive size S = next_pow2(gc) (entries >= gc are never read by nms_out).
// R6 A/B: adaptive sort saved ~50us vs fixed S=4096.
__global__ __launch_bounds__(1024) void sort_cand(int* __restrict__ gcount,
                                                  unsigned long long* __restrict__ gkeys) {
    __shared__ unsigned long long sk[CAP];
    int b = blockIdx.x, tid = threadIdx.x;
    int gc = gcount[b]; if (gc > CAP) gc = CAP;
    int S = 1024;
    while (S < gc) S <<= 1;              // uniform per block
    for (int i = tid; i < S; i += 1024)
        sk[i] = (i < gc) ? gkeys[(size_t)b * CAP + i] : ~0ULL;
    __syncthreads();
    for (int k = 2; k <= S; k <<= 1) {
        for (int j = k >> 1; j > 0; j >>= 1) {
            for (int i = tid; i < S; i += 1024) {
                int ixj = i ^ j;
                if (ixj > i) {
                    bool up = ((i & k) == 0);
                    unsigned long long a = sk[i], c = sk[ixj];
                    if ((a > c) == up) { sk[i] = c; sk[ixj] = a; }
                }
            }
            __syncthreads();
        }
    }
    for (int i = tid; i < S; i += 1024)
        gkeys[(size_t)b * CAP + i] = sk[i];
    if (tid == 0 && gcount[b] > CAP) gcount[b] = CAP;
}

// ---------------- serial greedy NMS scan + output ----------------
// R7: PRE-DECODE the first NPRE sorted candidates into LDS in parallel (the box
// decode is independent of keep decisions). The serial iteration drops from
// {2 chained global L2 reads (~200cy each) + 2 expf + IoU} to {LDS box read + IoU}
// -- roughly halving the dependent critical path of the ~300-800-iteration scan.
// decode4 ops are computed identically (just earlier) => bitwise-identical output.
// Past NPRE falls back to on-the-fly global decode (correctness; rarely reached).
#define NPRE 2048
__global__ __launch_bounds__(64) void nms_out(const unsigned long long* __restrict__ gkeys,
                                              const int* __restrict__ gcount,
                                              const float* __restrict__ scores,
                                              const float* __restrict__ logreg,
                                              const float* __restrict__ proposals,
                                              float* __restrict__ out) {
    int b = blockIdx.x, tid = threadIdx.x;
    __shared__ float bx1[NPRE], by1[NPRE], bx2[NPRE], by2[NPRE];   // 32 KB
    __shared__ unsigned int scand[NPRE];                           // 8 KB
    __shared__ float kbox[KKEEP][4];
    __shared__ int   kcls[KKEEP];
    __shared__ int   kcand[KKEEP];
    __shared__ int   kcount;
    if (tid == 0) kcount = 0;
    int gc = min(gcount[b], CAP);
    int pre = min(gc, NPRE);
    for (int i = tid; i < pre; i += 64) {
        unsigned long long key = gkeys[(size_t)b * CAP + i];
        unsigned int cand = (unsigned int)(key & 0xFFFFFFFFULL);
        int n = cand / 10;
        int c = (int)(cand - n * 10) + 1;
        int r = b * NPROP + n;
        float x1, y1, x2, y2;
        decode4(proposals + (size_t)r * 9, logreg + (size_t)r * LRLD + 11 + c * 9,
                x1, y1, x2, y2);
        bx1[i] = x1; by1[i] = y1; bx2[i] = x2; by2[i] = y2;
        scand[i] = cand;
    }
    __syncthreads();
    for (int ptr = 0; ptr < gc; ++ptr) {
        __syncthreads();
        int kc = kcount;
        if (kc >= KKEEP) break;
        float x1, y1, x2, y2;
        unsigned int cand;
        if (ptr < NPRE) {
            x1 = bx1[ptr]; y1 = by1[ptr]; x2 = bx2[ptr]; y2 = by2[ptr];
            cand = scand[ptr];
        } else {
            unsigned long long key = gkeys[(size_t)b * CAP + ptr];
            cand = (unsigned int)(key & 0xFFFFFFFFULL);
            int n2 = cand / 10;
            int c2 = (int)(cand - n2 * 10) + 1;
            int r2 = b * NPROP + n2;
            decode4(proposals + (size_t)r2 * 9, logreg + (size_t)r2 * LRLD + 11 + c2 * 9,
                    x1, y1, x2, y2);
        }
        int c = (int)(cand - (cand / 10u) * 10u) + 1;
        int sup = 0;
        for (int q = tid; q < kc; q += 64) {
            if (kcls[q] == c) {
                float xx1 = fmaxf(x1, kbox[q][0]);
                float yy1 = fmaxf(y1, kbox[q][1]);
                float xx2 = fminf(x2, kbox[q][2]);
                float yy2 = fminf(y2, kbox[q][3]);
                float inter = fmaxf(xx2 - xx1, 0.f) * fmaxf(yy2 - yy1, 0.f);
                float aa = (kbox[q][2] - kbox[q][0]) * (kbox[q][3] - kbox[q][1]);
                float ab = (x2 - x1) * (y2 - y1);
                float iou = inter / (aa + ab - inter + 1e-9f);
                if (iou > NMS_T) sup = 1;
            }
        }
        if (!__any(sup)) {
            if (tid == 0) {
                kbox[kc][0] = x1; kbox[kc][1] = y1; kbox[kc][2] = x2; kbox[kc][3] = y2;
                kcls[kc] = c; kcand[kc] = (int)cand; kcount = kc + 1;
            }
        }
    }
    __syncthreads();
    int kc = min(kcount, KKEEP);
    for (int k = tid; k < KKEEP; k += 64) {
        int cand = (k < kc) ? kcand[k] : 0;     // exhausted list => argmax of all -inf = idx 0
        int n = cand / 10;
        int c = cand - n * 10 + 1;
        int r = b * NPROP + n;
        const float* prop = proposals + (size_t)r * 9;
        const float* rg = logreg + (size_t)r * LRLD + 11 + c * 9;
        float x1, y1, x2, y2;
        decode4(prop, rg, x1, y1, x2, y2);
        float* ob = out + ((size_t)b * KKEEP + k) * 9;
        ob[0] = x1; ob[1] = y1; ob[2] = x2; ob[3] = y2;
#pragma unroll
        for (int j = 0; j < 5; ++j) ob[4 + j] = prop[4 + j] + rg[4 + j];
        out[NFRAMES * KKEEP * 9 + b * KKEEP + k] =
            (k < kc) ? scores[(size_t)r * 10 + (c - 1)] : 0.f;
        out[NFRAMES * KKEEP * 9 + NFRAMES * KKEEP + b * KKEEP + k] =
            (k < kc) ? (float)c : -1.0f;
    }
}

// ---------------- host launch ----------------
extern "C" void kernel_launch(void* const* d_in, const int* in_sizes, int n_in,
                              void* d_out, int out_size, void* d_ws, size_t ws_size,
                              hipStream_t stream) {
    (void)in_sizes; (void)n_in; (void)out_size;
    if (ws_size < WS_NEEDED) return;

    const float* x         = (const float*)d_in[0];
    const float* proposals = (const float*)d_in[1];
    const float* w1        = (const float*)d_in[2];
    const float* b1        = (const float*)d_in[3];
    const float* w2        = (const float*)d_in[4];
    const float* b2        = (const float*)d_in[5];
    const float* wc        = (const float*)d_in[6];
    const float* bc        = (const float*)d_in[7];
    const float* wr        = (const float*)d_in[8];
    const float* br        = (const float*)d_in[9];
    float* out = (float*)d_out;

    char* ws = (char*)d_ws;
    float* h1     = (float*)(ws + OFF_H1);
    float* h2     = (float*)(ws + OFF_H2);
    float* logreg = (float*)(ws + OFF_LR);
    float* wcat   = (float*)(ws + OFF_WCAT);
    float* bcat   = (float*)(ws + OFF_BCAT);
    float* scores = (float*)(ws + OFF_SCORES);
    int*   hist   = (int*)(ws + OFF_HIST);
    int*   gcount = (int*)(ws + OFF_GCNT);
    int*   taubin = (int*)(ws + OFF_TAU);
    unsigned long long* gkeys = (unsigned long long*)(ws + OFF_GKEYS);

    // zero hist + gcount + taubin (ws is poisoned before every call)
    hipMemsetAsync(hist, 0, (size_t)(NFRAMES * NBINS * 4 + 256), stream);

    concat_w<<<(HDIM * LRLD + 255) / 256, 256, 0, stream>>>(wc, bc, wr, br, wcat, bcat);

    gemm128<<<dim3(NROWS / 128, HDIM / 128), 256, 0, stream>>>(x,  w1,   b1,   h1,     DIN_, HDIM, 1);
    gemm128<<<dim3(NROWS / 128, HDIM / 128), 256, 0, stream>>>(h1, w2,   b2,   h2,     HDIM, HDIM, 1);
    gemm128<<<dim3(NROWS / 128, 1),          256, 0, stream>>>(h2, wcat, bcat, logreg, HDIM, LRLD, 0);

    softmax_hist<<<NROWS / 256, 256, 0, stream>>>(logreg, scores, hist);
    select_tau<<<NFRAMES, 1024, 0, stream>>>(hist, taubin);
    gather_cand<<<(NROWS * 10 + 255) / 256, 256, 0, stream>>>(scores, logreg, proposals,
                                                              taubin, gcount, gkeys);
    sort_cand<<<NFRAMES, 1024, 0, stream>>>(gcount, gkeys);
    nms_out<<<NFRAMES, 64, 0, stream>>>(gkeys, gcount, scores, logreg, proposals, out);
}

// Round 9
// 919.201 us; speedup vs baseline: 1.8942x; 1.0245x over previous
//
#include <hip/hip_runtime.h>
#include <stdint.h>

// ---------------- problem constants ----------------
#define NFRAMES 2
#define NPROP   16384
#define NROWS   (NFRAMES * NPROP)        // 32768
#define DIN_    1024
#define HDIM    512
#define NCLS    11
#define LRLD    128                      // padded cols of [logits(11) | reg(99) | pad]
#define NBINS   8192
#define CAP     4096                     // gathered candidate capacity per frame
#define TGT     1024                     // target top-N for NMS scan
#define KKEEP   100
#define SCORE_T 0.05f
#define NMS_T   0.5f
#define CLIPV   4.135166556742356f       // log(1000/16)
#define BK      16

// ---------------- workspace layout (bytes) ----------------
#define OFF_H1      0ULL                           // 32768*512 f32
#define OFF_H2      67108864ULL                    // 32768*512 f32
#define OFF_LR      134217728ULL                   // 32768*128 f32
#define OFF_WCAT    150994944ULL                   // 512*128 f32
#define OFF_BCAT    151257088ULL                   // 128 f32 (padded)
#define OFF_SCORES  151258112ULL                   // 32768*10 f32
#define OFF_HIST    152568832ULL                   // 2*8192 i32
#define OFF_GCNT    152634368ULL                   // 2 i32
#define OFF_TAU     152634376ULL                   // 2 i32
#define OFF_GKEYS   152634624ULL                   // 2*4096 u64
#define WS_NEEDED   152700160ULL

// ---------------- box decode (must match reference float ops) ----------------
__device__ __forceinline__ void decode4(const float* __restrict__ prop,
                                        const float* __restrict__ rg,
                                        float& x1, float& y1, float& x2, float& y2) {
    float w  = prop[2] - prop[0];
    float h  = prop[3] - prop[1];
    float cx = prop[0] + 0.5f * w;
    float cy = prop[1] + 0.5f * h;
    float dx = rg[0] / 10.0f;
    float dy = rg[1] / 10.0f;
    float dw = fminf(rg[2] / 5.0f, CLIPV);
    float dh = fminf(rg[3] / 5.0f, CLIPV);
    float pcx = dx * w + cx;
    float pcy = dy * h + cy;
    float pw  = expf(dw) * w;
    float ph  = expf(dh) * h;
    x1 = pcx - 0.5f * pw;
    y1 = pcy - 0.5f * ph;
    x2 = pcx + 0.5f * pw;
    y2 = pcy + 0.5f * ph;
}

// ---------------- fp32 GEMM: C[M,N] = act(A[M,K]@B[K,N] + bias) ----------------
// FROZEN at the R2 champion source (423 us GEMM1, VALU 67.6% = its exact
// LDS-pipe model ceiling: per kk, VALU 128 cyc/SIMD vs LDS 192 cyc/CU).
// R3-R8 post-mortems: every perturbation regressed 13-130%. Do not touch.
__global__ __launch_bounds__(256) void gemm128(const float* __restrict__ A,
                                               const float* __restrict__ B,
                                               const float* __restrict__ bias,
                                               float* __restrict__ C,
                                               int K, int N, int do_relu) {
    __shared__ float As[2][BK][128];   // 16 KB
    __shared__ float Bs[2][BK][128];   // 16 KB
    const int tid  = threadIdx.x;
    const int row0 = blockIdx.x * 128;
    const int col0 = blockIdx.y * 128;
    const int tx = tid & 15, ty = tid >> 4;

    // A staging: thread -> row (tid>>1), 8 consecutive K floats at (tid&1)*8
    const int arow  = tid >> 1;
    const int akoff = (tid & 1) * 8;
    // B staging: thread -> rows (tid>>5) and (tid>>5)+8, float4 col (tid&31)*4
    const int brow  = tid >> 5;
    const int bc4   = (tid & 31) * 4;

    const float* Ap = A + (size_t)(row0 + arow) * K + akoff;
    const float* Bp = B + col0 + bc4;

    float acc[8][8];
#pragma unroll
    for (int i = 0; i < 8; ++i)
#pragma unroll
        for (int j = 0; j < 8; ++j) acc[i][j] = 0.f;

    // prologue: load tile 0 into regs, write LDS[0]
    float4 a0 = *(const float4*)(Ap + 0);
    float4 a1 = *(const float4*)(Ap + 4);
    float4 b0 = *(const float4*)(Bp + (size_t)brow * N);
    float4 b1 = *(const float4*)(Bp + (size_t)(brow + 8) * N);
    As[0][akoff + 0][arow] = a0.x;
    As[0][akoff + 1][arow] = a0.y;
    As[0][akoff + 2][arow] = a0.z;
    As[0][akoff + 3][arow] = a0.w;
    As[0][akoff + 4][arow] = a1.x;
    As[0][akoff + 5][arow] = a1.y;
    As[0][akoff + 6][arow] = a1.z;
    As[0][akoff + 7][arow] = a1.w;
    *(float4*)&Bs[0][brow][bc4]     = b0;
    *(float4*)&Bs[0][brow + 8][bc4] = b1;
    __syncthreads();

    int p = 0;
    for (int k0 = 0; k0 < K; k0 += BK) {
        const bool has_next = (k0 + BK) < K;
        if (has_next) {   // prefetch next tile into regs; consumed after 16*64 FMAs
            a0 = *(const float4*)(Ap + k0 + BK);
            a1 = *(const float4*)(Ap + k0 + BK + 4);
            b0 = *(const float4*)(Bp + (size_t)(k0 + BK + brow) * N);
            b1 = *(const float4*)(Bp + (size_t)(k0 + BK + brow + 8) * N);
        }
#pragma unroll
        for (int kk = 0; kk < BK; ++kk) {
            float4 x0 = *(const float4*)&As[p][kk][ty * 4];
            float4 x1 = *(const float4*)&As[p][kk][64 + ty * 4];
            float4 y0 = *(const float4*)&Bs[p][kk][tx * 4];
            float4 y1 = *(const float4*)&Bs[p][kk][64 + tx * 4];
            float ar[8] = {x0.x, x0.y, x0.z, x0.w, x1.x, x1.y, x1.z, x1.w};
            float br[8] = {y0.x, y0.y, y0.z, y0.w, y1.x, y1.y, y1.z, y1.w};
#pragma unroll
            for (int i = 0; i < 8; ++i)
#pragma unroll
                for (int j = 0; j < 8; ++j) acc[i][j] += ar[i] * br[j];
        }
        if (has_next) {
            const int q = p ^ 1;   // writes target the buffer whose reads finished
            As[q][akoff + 0][arow] = a0.x;   // before the PREVIOUS barrier
            As[q][akoff + 1][arow] = a0.y;
            As[q][akoff + 2][arow] = a0.z;
            As[q][akoff + 3][arow] = a0.w;
            As[q][akoff + 4][arow] = a1.x;
            As[q][akoff + 5][arow] = a1.y;
            As[q][akoff + 6][arow] = a1.z;
            As[q][akoff + 7][arow] = a1.w;
            *(float4*)&Bs[q][brow][bc4]     = b0;
            *(float4*)&Bs[q][brow + 8][bc4] = b1;
            __syncthreads();
            p = q;
        }
    }

#pragma unroll
    for (int qi = 0; qi < 2; ++qi)
#pragma unroll
        for (int i = 0; i < 4; ++i) {
            int row = row0 + qi * 64 + ty * 4 + i;
#pragma unroll
            for (int qj = 0; qj < 2; ++qj) {
                int col = col0 + qj * 64 + tx * 4;
                float4 v;
                v.x = acc[qi * 4 + i][qj * 4 + 0] + bias[col + 0];
                v.y = acc[qi * 4 + i][qj * 4 + 1] + bias[col + 1];
                v.z = acc[qi * 4 + i][qj * 4 + 2] + bias[col + 2];
                v.w = acc[qi * 4 + i][qj * 4 + 3] + bias[col + 3];
                if (do_relu) {
                    v.x = fmaxf(v.x, 0.f); v.y = fmaxf(v.y, 0.f);
                    v.z = fmaxf(v.z, 0.f); v.w = fmaxf(v.w, 0.f);
                }
                *(float4*)(C + (size_t)row * N + col) = v;
            }
        }
}

// ---------------- concat wc|wr into [512][128] (zero padded), same for bias ----------------
__global__ void concat_w(const float* __restrict__ wc, const float* __restrict__ bc,
                         const float* __restrict__ wr, const float* __restrict__ br,
                         float* __restrict__ wcat, float* __restrict__ bcat) {
    int gid = blockIdx.x * 256 + threadIdx.x;
    if (gid >= HDIM * LRLD) return;
    int k = gid >> 7, j = gid & 127;
    float v = 0.f;
    if (j < 11)       v = wc[k * 11 + j];
    else if (j < 110) v = wr[k * 99 + (j - 11)];
    wcat[gid] = v;
    if (k == 0) {
        float b = 0.f;
        if (j < 11)       b = bc[j];
        else if (j < 110) b = br[j - 11];
        bcat[j] = b;
    }
}

// ---------------- softmax + score histogram ----------------
// R9 (kept from R8): full-GPU grid -- 256 blocks x 128 rows (was 128 blocks = half
// the CUs idle). Order-independent: histogram atomics commute, score writes are
// per-row exclusive; per-row math identical => bitwise-identical scores.
__global__ __launch_bounds__(256) void softmax_hist(const float* __restrict__ logreg,
                                                    float* __restrict__ scores,
                                                    int* __restrict__ hist) {
    __shared__ int lh[NBINS];   // 32 KB
    const int t = threadIdx.x;
    for (int i = t; i < NBINS; i += 256) lh[i] = 0;
    __syncthreads();

    if (t < 128) {
        const int r = blockIdx.x * 128 + t;
        const float* lr = logreg + (size_t)r * LRLD;
        float4 v0 = *(const float4*)(lr);
        float4 v1 = *(const float4*)(lr + 4);
        float4 v2 = *(const float4*)(lr + 8);
        float l[NCLS] = {v0.x, v0.y, v0.z, v0.w, v1.x, v1.y, v1.z, v1.w, v2.x, v2.y, v2.z};
        float m = l[0];
#pragma unroll
        for (int j = 1; j < NCLS; ++j) m = fmaxf(m, l[j]);
        float e[NCLS]; float s = 0.f;
#pragma unroll
        for (int j = 0; j < NCLS; ++j) { e[j] = expf(l[j] - m); s += e[j]; }
#pragma unroll
        for (int c = 1; c < NCLS; ++c) {
            float p = e[c] / s;
            scores[(size_t)r * 10 + (c - 1)] = p;
            if (p > SCORE_T) {
                int bin = (int)(p * (float)NBINS);
                bin = min(max(bin, 0), NBINS - 1);
                atomicAdd(&lh[bin], 1);
            }
        }
    }
    __syncthreads();
    const int b = (blockIdx.x * 128) >> 14;
    for (int i = t; i < NBINS; i += 256) {
        int c = lh[i];
        if (c) atomicAdd(&hist[b * NBINS + i], c);
    }
}

// ---------------- find histogram bin threshold covering top >= TGT ----------------
__global__ __launch_bounds__(1024) void select_tau(const int* __restrict__ hist,
                                                   int* __restrict__ taubin) {
    __shared__ int seg[1024];
    __shared__ int best;
    const int b = blockIdx.x, t = threadIdx.x;
    if (t == 0) best = 0;
    const int base = t * 8;
    int loc[8];
    int s = 0;
#pragma unroll
    for (int i = 7; i >= 0; --i) {       // loc[i] = hist[base+i] + ... + hist[base+7]
        s += hist[b * NBINS + base + i];
        loc[i] = s;
    }
    seg[t] = s;
    __syncthreads();
    // inclusive suffix scan over seg: seg[t] = sum seg_orig[t..1023]
    for (int off = 1; off < 1024; off <<= 1) {
        int v = (t + off < 1024) ? seg[t + off] : 0;
        __syncthreads();
        seg[t] += v;
        __syncthreads();
    }
    const int above = (t + 1 < 1024) ? seg[t + 1] : 0;
    int bmax = -1;
#pragma unroll
    for (int i = 0; i < 8; ++i) {
        if (loc[i] + above >= TGT) bmax = base + i;
    }
    if (bmax >= 0) atomicMax(&best, bmax);
    __syncthreads();
    if (t == 0) taubin[b] = best;
}

// ---------------- gather top candidates as sortable keys ----------------
__global__ void gather_cand(const float* __restrict__ scores,
                            const float* __restrict__ logreg,
                            const float* __restrict__ proposals,
                            const int* __restrict__ taubin,
                            int* __restrict__ gcount,
                            unsigned long long* __restrict__ gkeys) {
    int gid = blockIdx.x * 256 + threadIdx.x;
    if (gid >= NROWS * 10) return;
    int r  = gid / 10;
    int ci = gid - r * 10;          // class-1
    int b  = r >> 14;
    float p = scores[gid];
    int bin = (int)(p * (float)NBINS);
    bin = min(max(bin, 0), NBINS - 1);
    if (bin < taubin[b]) return;
    if (!(p > SCORE_T)) return;
    float x1, y1, x2, y2;
    decode4(proposals + (size_t)r * 9, logreg + (size_t)r * LRLD + 11 + (ci + 1) * 9,
            x1, y1, x2, y2);
    if (!((x2 - x1) >= 0.01f && (y2 - y1) >= 0.01f)) return;
    int pos = atomicAdd(&gcount[b], 1);
    if (pos < CAP) {
        unsigned int sb   = __float_as_uint(p);                 // p > 0 => order-preserving
        unsigned int cand = (unsigned)(r - b * NPROP) * 10u + (unsigned)ci;
        // ascending sort => score desc (inverted bits), then cand asc (argmax tie-break)
        gkeys[(size_t)b * CAP + pos] =
            ((unsigned long long)(0xFFFFFFFFu - sb) << 32) | (unsigned long long)cand;
    }
}

// ---------------- bitonic sort of candidate keys per frame ----------------
// Adaptive size S = next_pow2(gc) (entries >= gc are never read by nms_out).
__global__ __launch_bounds__(1024) void sort_cand(int* __restrict__ gcount,
                                                  unsigned long long* __restrict__ gkeys) {
    __shared__ unsigned long long sk[CAP];
    int b = blockIdx.x, tid = threadIdx.x;
    int gc = gcount[b]; if (gc > CAP) gc = CAP;
    int S = 1024;
    while (S < gc) S <<= 1;              // uniform per block
    for (int i = tid; i < S; i += 1024)
        sk[i] = (i < gc) ? gkeys[(size_t)b * CAP + i] : ~0ULL;
    __syncthreads();
    for (int k = 2; k <= S; k <<= 1) {
        for (int j = k >> 1; j > 0; j >>= 1) {
            for (int i = tid; i < S; i += 1024) {
                int ixj = i ^ j;
                if (ixj > i) {
                    bool up = ((i & k) == 0);
                    unsigned long long a = sk[i], c = sk[ixj];
                    if ((a > c) == up) { sk[i] = c; sk[ixj] = a; }
                }
            }
            __syncthreads();
        }
    }
    for (int i = tid; i < S; i += 1024)
        gkeys[(size_t)b * CAP + i] = sk[i];
    if (tid == 0 && gcount[b] > CAP) gcount[b] = CAP;
}

// ---------------- serial greedy NMS scan + output ----------------
// R7 version VERBATIM (passed, 941.7us). R8's barrier removal FAILED (absmax 487):
// __shared__ is not volatile -- without the per-iteration __syncthreads the
// compiler legally hoists/caches the cross-lane kcount/kbox reads (the writes
// come from a DIFFERENT lane; __any() is a ballot, not a memory fence).
// The in-loop barriers are load-bearing. Do not remove.
#define NPRE 2048
__global__ __launch_bounds__(64) void nms_out(const unsigned long long* __restrict__ gkeys,
                                              const int* __restrict__ gcount,
                                              const float* __restrict__ scores,
                                              const float* __restrict__ logreg,
                                              const float* __restrict__ proposals,
                                              float* __restrict__ out) {
    int b = blockIdx.x, tid = threadIdx.x;
    __shared__ float bx1[NPRE], by1[NPRE], bx2[NPRE], by2[NPRE];   // 32 KB
    __shared__ unsigned int scand[NPRE];                           // 8 KB
    __shared__ float kbox[KKEEP][4];
    __shared__ int   kcls[KKEEP];
    __shared__ int   kcand[KKEEP];
    __shared__ int   kcount;
    if (tid == 0) kcount = 0;
    int gc = min(gcount[b], CAP);
    int pre = min(gc, NPRE);
    for (int i = tid; i < pre; i += 64) {
        unsigned long long key = gkeys[(size_t)b * CAP + i];
        unsigned int cand = (unsigned int)(key & 0xFFFFFFFFULL);
        int n = cand / 10;
        int c = (int)(cand - n * 10) + 1;
        int r = b * NPROP + n;
        float x1, y1, x2, y2;
        decode4(proposals + (size_t)r * 9, logreg + (size_t)r * LRLD + 11 + c * 9,
                x1, y1, x2, y2);
        bx1[i] = x1; by1[i] = y1; bx2[i] = x2; by2[i] = y2;
        scand[i] = cand;
    }
    __syncthreads();
    for (int ptr = 0; ptr < gc; ++ptr) {
        __syncthreads();
        int kc = kcount;
        if (kc >= KKEEP) break;
        float x1, y1, x2, y2;
        unsigned int cand;
        if (ptr < NPRE) {
            x1 = bx1[ptr]; y1 = by1[ptr]; x2 = bx2[ptr]; y2 = by2[ptr];
            cand = scand[ptr];
        } else {
            unsigned long long key = gkeys[(size_t)b * CAP + ptr];
            cand = (unsigned int)(key & 0xFFFFFFFFULL);
            int n2 = cand / 10;
            int c2 = (int)(cand - n2 * 10) + 1;
            int r2 = b * NPROP + n2;
            decode4(proposals + (size_t)r2 * 9, logreg + (size_t)r2 * LRLD + 11 + c2 * 9,
                    x1, y1, x2, y2);
        }
        int c = (int)(cand - (cand / 10u) * 10u) + 1;
        int sup = 0;
        for (int q = tid; q < kc; q += 64) {
            if (kcls[q] == c) {
                float xx1 = fmaxf(x1, kbox[q][0]);
                float yy1 = fmaxf(y1, kbox[q][1]);
                float xx2 = fminf(x2, kbox[q][2]);
                float yy2 = fminf(y2, kbox[q][3]);
                float inter = fmaxf(xx2 - xx1, 0.f) * fmaxf(yy2 - yy1, 0.f);
                float aa = (kbox[q][2] - kbox[q][0]) * (kbox[q][3] - kbox[q][1]);
                float ab = (x2 - x1) * (y2 - y1);
                float iou = inter / (aa + ab - inter + 1e-9f);
                if (iou > NMS_T) sup = 1;
            }
        }
        if (!__any(sup)) {
            if (tid == 0) {
                kbox[kc][0] = x1; kbox[kc][1] = y1; kbox[kc][2] = x2; kbox[kc][3] = y2;
                kcls[kc] = c; kcand[kc] = (int)cand; kcount = kc + 1;
            }
        }
    }
    __syncthreads();
    int kc = min(kcount, KKEEP);
    for (int k = tid; k < KKEEP; k += 64) {
        int cand = (k < kc) ? kcand[k] : 0;     // exhausted list => argmax of all -inf = idx 0
        int n = cand / 10;
        int c = cand - n * 10 + 1;
        int r = b * NPROP + n;
        const float* prop = proposals + (size_t)r * 9;
        const float* rg = logreg + (size_t)r * LRLD + 11 + c * 9;
        float x1, y1, x2, y2;
        decode4(prop, rg, x1, y1, x2, y2);
        float* ob = out + ((size_t)b * KKEEP + k) * 9;
        ob[0] = x1; ob[1] = y1; ob[2] = x2; ob[3] = y2;
#pragma unroll
        for (int j = 0; j < 5; ++j) ob[4 + j] = prop[4 + j] + rg[4 + j];
        out[NFRAMES * KKEEP * 9 + b * KKEEP + k] =
            (k < kc) ? scores[(size_t)r * 10 + (c - 1)] : 0.f;
        out[NFRAMES * KKEEP * 9 + NFRAMES * KKEEP + b * KKEEP + k] =
            (k < kc) ? (float)c : -1.0f;
    }
}

// ---------------- host launch ----------------
extern "C" void kernel_launch(void* const* d_in, const int* in_sizes, int n_in,
                              void* d_out, int out_size, void* d_ws, size_t ws_size,
                              hipStream_t stream) {
    (void)in_sizes; (void)n_in; (void)out_size;
    if (ws_size < WS_NEEDED) return;

    const float* x         = (const float*)d_in[0];
    const float* proposals = (const float*)d_in[1];
    const float* w1        = (const float*)d_in[2];
    const float* b1        = (const float*)d_in[3];
    const float* w2        = (const float*)d_in[4];
    const float* b2        = (const float*)d_in[5];
    const float* wc        = (const float*)d_in[6];
    const float* bc        = (const float*)d_in[7];
    const float* wr        = (const float*)d_in[8];
    const float* br        = (const float*)d_in[9];
    float* out = (float*)d_out;

    char* ws = (char*)d_ws;
    float* h1     = (float*)(ws + OFF_H1);
    float* h2     = (float*)(ws + OFF_H2);
    float* logreg = (float*)(ws + OFF_LR);
    float* wcat   = (float*)(ws + OFF_WCAT);
    float* bcat   = (float*)(ws + OFF_BCAT);
    float* scores = (float*)(ws + OFF_SCORES);
    int*   hist   = (int*)(ws + OFF_HIST);
    int*   gcount = (int*)(ws + OFF_GCNT);
    int*   taubin = (int*)(ws + OFF_TAU);
    unsigned long long* gkeys = (unsigned long long*)(ws + OFF_GKEYS);

    // zero hist + gcount + taubin (ws is poisoned before every call)
    hipMemsetAsync(hist, 0, (size_t)(NFRAMES * NBINS * 4 + 256), stream);

    concat_w<<<(HDIM * LRLD + 255) / 256, 256, 0, stream>>>(wc, bc, wr, br, wcat, bcat);

    gemm128<<<dim3(NROWS / 128, HDIM / 128), 256, 0, stream>>>(x,  w1,   b1,   h1,     DIN_, HDIM, 1);
    gemm128<<<dim3(NROWS / 128, HDIM / 128), 256, 0, stream>>>(h1, w2,   b2,   h2,     HDIM, HDIM, 1);
    gemm128<<<dim3(NROWS / 128, 1),          256, 0, stream>>>(h2, wcat, bcat, logreg, HDIM, LRLD, 0);

    softmax_hist<<<NROWS / 128, 256, 0, stream>>>(logreg, scores, hist);
    select_tau<<<NFRAMES, 1024, 0, stream>>>(hist, taubin);
    gather_cand<<<(NROWS * 10 + 255) / 256, 256, 0, stream>>>(scores, logreg, proposals,
                                                              taubin, gcount, gkeys);
    sort_cand<<<NFRAMES, 1024, 0, stream>>>(gcount, gkeys);
    nms_out<<<NFRAMES, 64, 0, stream>>>(gkeys, gcount, scores, logreg, proposals, out);
}